// Round 1
// baseline (529.220 us; speedup 1.0000x reference)
//
#include <hip/hip_runtime.h>

// Sizes fixed by the problem: B=8, H=W=512, C=F=16, N_POOL=8, pooled W=256.
#define NB 8
#define NH 512
#define NW 512
#define NC 16
#define NPOOL 8
#define NW2 256
#define POOL_ELEMS (NB * NPOOL * NW2 * NC)   // 262144

// ---------------------------------------------------------------------------
// Kernel 1: average pool (64,2) -> pooled [B, 8, 256, 16]
// Grid: B*8*8 = 512 blocks, 256 threads. Each block: (b, n, 64-wide w tile).
// Thread t: w_local = t>>2 (0..63), c-quad = t&3. Accumulate 64 rows, then
// shfl_xor(4) combines the w-pair; half the threads write.
// ---------------------------------------------------------------------------
__global__ __launch_bounds__(256) void pool_k(const float* __restrict__ fm,
                                              float* __restrict__ pooled) {
  int bid = blockIdx.x;
  int wt = bid & 7;          // w tile (64 wide)
  int n  = (bid >> 3) & 7;   // pool row
  int b  = bid >> 6;
  int t = threadIdx.x;
  int wl = t >> 2;           // 0..63
  int cq = t & 3;            // c quad
  int w = wt * 64 + wl;

  const float* src = fm + ((size_t)((b * NH + n * 64) * NW + w) * NC + cq * 4);
  float4 a = make_float4(0.f, 0.f, 0.f, 0.f);
#pragma unroll 8
  for (int dh = 0; dh < 64; ++dh) {
    float4 v = *(const float4*)(src + (size_t)dh * (NW * NC));
    a.x += v.x; a.y += v.y; a.z += v.z; a.w += v.w;
  }
  // combine w and w+1 (threads t and t^4 share cq, differ by 1 in w_local)
  a.x += __shfl_xor(a.x, 4);
  a.y += __shfl_xor(a.y, 4);
  a.z += __shfl_xor(a.z, 4);
  a.w += __shfl_xor(a.w, 4);
  if ((t & 4) == 0) {
    int w2 = wt * 32 + (t >> 3);
    const float s = 1.f / 128.f;
    float4 r = make_float4(a.x * s, a.y * s, a.z * s, a.w * s);
    *(float4*)(pooled + ((size_t)((b * NPOOL + n) * NW2 + w2) * NC + cq * 4)) = r;
  }
}

// ---------------------------------------------------------------------------
// Kernel 2: masked 3x3 conv (middle kernel row zeroed) on pooled, both in the
// original orientation (row_op) and spatial-transposed orientation (col_op).
//   row_op[n,w2,f] = sum_{kh in {0,2}, kw, c} P[n+kh-1, w2+kw-1, c] K[kh,kw,c,f]
//   col_op[n,w2,f] = sum_{kh in {0,2}, kw, c} P[n+kw-1, w2+kh-1, c] K[kh,kw,c,f]
// Both use the SAME 6 kernel taps. Thread per (b,n,w2,f): 262144 threads.
// ---------------------------------------------------------------------------
__global__ __launch_bounds__(256) void conv_k(const float* __restrict__ pooled,
                                              const float* __restrict__ kern,
                                              const float* __restrict__ bias,
                                              float* __restrict__ row_op,
                                              float* __restrict__ col_op) {
  int idx = blockIdx.x * 256 + threadIdx.x;
  int f  = idx & 15;
  int w2 = (idx >> 4) & 255;
  int n  = (idx >> 12) & 7;
  int b  = idx >> 15;

  bool nm = n > 0, npv = n < 7, wm = w2 > 0, wp = w2 < 255;
  const float* P = pooled + (size_t)((b * NPOOL + n) * NW2 + w2) * NC;
  const int UP = -NW2 * NC, DN = NW2 * NC, LT = -NC, RT = NC;

  float accR = bias[f];
  float accC = accR;
#pragma unroll
  for (int c = 0; c < 16; ++c) {
    float tl = (nm && wm) ? P[UP + LT + c] : 0.f;
    float tc = nm         ? P[UP + c]      : 0.f;
    float tr = (nm && wp) ? P[UP + RT + c] : 0.f;
    float ml = wm         ? P[LT + c]      : 0.f;
    float mr = wp         ? P[RT + c]      : 0.f;
    float bl = (npv && wm) ? P[DN + LT + c] : 0.f;
    float bc = npv         ? P[DN + c]      : 0.f;
    float br = (npv && wp) ? P[DN + RT + c] : 0.f;

    float k00 = kern[((0 * 3 + 0) * 16 + c) * 16 + f];
    float k01 = kern[((0 * 3 + 1) * 16 + c) * 16 + f];
    float k02 = kern[((0 * 3 + 2) * 16 + c) * 16 + f];
    float k20 = kern[((2 * 3 + 0) * 16 + c) * 16 + f];
    float k21 = kern[((2 * 3 + 1) * 16 + c) * 16 + f];
    float k22 = kern[((2 * 3 + 2) * 16 + c) * 16 + f];

    accR += tl * k00 + tc * k01 + tr * k02 + bl * k20 + bc * k21 + br * k22;
    accC += tl * k00 + ml * k01 + bl * k02 + tr * k20 + mr * k21 + br * k22;
  }
  row_op[idx] = fmaxf(accR, 0.f);
  col_op[idx] = fmaxf(accC, 0.f);
}

// ---------------------------------------------------------------------------
// Kernel 3: bilinear upsample row_op/col_op to [512,512], diff vs fm, write
// out[b,h,w, 0:16]=fm, [16:32]=fm-row_up, [32:48]=fm-col_up.
// Block = 64 consecutive pixels of one image row; 4 threads per pixel (one
// c-quad each). Results staged in LDS [64][48] so global writes are 3 fully
// contiguous float4 stores per thread (perfect coalescing over 12 KB/block).
// ---------------------------------------------------------------------------
__global__ __launch_bounds__(256) void out_k(const float* __restrict__ fm,
                                             const float* __restrict__ row_op,
                                             const float* __restrict__ col_op,
                                             float* __restrict__ out) {
  __shared__ float lds[64 * 48];
  int bid = blockIdx.x;
  int wt = bid & 7;
  int h  = (bid >> 3) & 511;
  int b  = bid >> 12;
  int t = threadIdx.x;
  int pl = t >> 2;   // local pixel 0..63
  int cq = t & 3;    // c quad
  int w = wt * 64 + pl;

  // interpolation coords (identical for row_up and col_up):
  // n-axis: 8 -> 512, w2-axis: 256 -> 512, half-pixel, edge-clamped.
  float x  = (h + 0.5f) * (1.f / 64.f) - 0.5f;
  float xf = floorf(x);
  float wx = x - xf;
  int n0  = (int)xf;
  int n0c = n0 < 0 ? 0 : n0;
  int n1c = (n0 + 1 > 7) ? 7 : n0 + 1;

  float y  = (w + 0.5f) * 0.5f - 0.5f;
  float yf = floorf(y);
  float wy = y - yf;
  int y0  = (int)yf;
  int y0c = y0 < 0 ? 0 : y0;
  int y1c = (y0 + 1 > 255) ? 255 : y0 + 1;

  float w00 = (1.f - wx) * (1.f - wy);
  float w01 = (1.f - wx) * wy;
  float w10 = wx * (1.f - wy);
  float w11 = wx * wy;

  size_t rowbase = (size_t)(b * NH + h) * NW;
  float4 fv = *(const float4*)(fm + (rowbase + w) * NC + cq * 4);

  const float* R  = row_op + (size_t)b * (NPOOL * NW2 * NC);
  const float* Cl = col_op + (size_t)b * (NPOOL * NW2 * NC);
#define TAP(A, nn, yy) (*(const float4*)((A) + ((size_t)(nn) * NW2 + (yy)) * NC + cq * 4))
  float4 r00 = TAP(R, n0c, y0c), r01 = TAP(R, n0c, y1c);
  float4 r10 = TAP(R, n1c, y0c), r11 = TAP(R, n1c, y1c);
  float4 c00 = TAP(Cl, n0c, y0c), c01 = TAP(Cl, n0c, y1c);
  float4 c10 = TAP(Cl, n1c, y0c), c11 = TAP(Cl, n1c, y1c);
#undef TAP

  float4 rup, cup;
  rup.x = w00 * r00.x + w01 * r01.x + w10 * r10.x + w11 * r11.x;
  rup.y = w00 * r00.y + w01 * r01.y + w10 * r10.y + w11 * r11.y;
  rup.z = w00 * r00.z + w01 * r01.z + w10 * r10.z + w11 * r11.z;
  rup.w = w00 * r00.w + w01 * r01.w + w10 * r10.w + w11 * r11.w;
  cup.x = w00 * c00.x + w01 * c01.x + w10 * c10.x + w11 * c11.x;
  cup.y = w00 * c00.y + w01 * c01.y + w10 * c10.y + w11 * c11.y;
  cup.z = w00 * c00.z + w01 * c01.z + w10 * c10.z + w11 * c11.z;
  cup.w = w00 * c00.w + w01 * c01.w + w10 * c10.w + w11 * c11.w;

  float* L = lds + pl * 48 + cq * 4;
  L[0]  = fv.x;          L[1]  = fv.y;          L[2]  = fv.z;          L[3]  = fv.w;
  L[16] = fv.x - rup.x;  L[17] = fv.y - rup.y;  L[18] = fv.z - rup.z;  L[19] = fv.w - rup.w;
  L[32] = fv.x - cup.x;  L[33] = fv.y - cup.y;  L[34] = fv.z - cup.z;  L[35] = fv.w - cup.w;
  __syncthreads();

  float* obase = out + ((size_t)(b * NH + h) * NW + wt * 64) * 48;
#pragma unroll
  for (int k = 0; k < 3; ++k) {
    int i = t + k * 256;
    *(float4*)(obase + (size_t)i * 4) = *(const float4*)(lds + i * 4);
  }
}

extern "C" void kernel_launch(void* const* d_in, const int* in_sizes, int n_in,
                              void* d_out, int out_size, void* d_ws, size_t ws_size,
                              hipStream_t stream) {
  const float* fm   = (const float*)d_in[0];
  const float* kern = (const float*)d_in[1];
  const float* bias = (const float*)d_in[2];
  float* out = (float*)d_out;

  float* pooled = (float*)d_ws;                 // 1 MB
  float* row_op = pooled + POOL_ELEMS;          // 1 MB
  float* col_op = row_op + POOL_ELEMS;          // 1 MB

  pool_k<<<NB * NPOOL * 8, 256, 0, stream>>>(fm, pooled);
  conv_k<<<POOL_ELEMS / 256, 256, 0, stream>>>(pooled, kern, bias, row_op, col_op);
  out_k<<<NB * NH * (NW / 64), 256, 0, stream>>>(fm, row_op, col_op, out);
}

// Round 3
// 505.203 us; speedup vs baseline: 1.0475x; 1.0475x over previous
//
#include <hip/hip_runtime.h>

// Sizes fixed by the problem: B=8, H=W=512, C=F=16, N_POOL=8, pooled W=256.
#define NB 8
#define NH 512
#define NW 512
#define NC 16
#define NPOOL 8
#define NW2 256
#define POOL_ELEMS (NB * NPOOL * NW2 * NC)   // 262144

typedef float vf4 __attribute__((ext_vector_type(4)));  // native vec for nontemporal

// ---------------------------------------------------------------------------
// Kernel 1: average pool (64,2) -> pooled [B, 8, 256, 16]
// Grid: 512 blocks (b, n, 64-wide w tile) x 1024 threads (4 row-groups of the
// 64-row window). Thread (rg, wl, cq) sums 16 rows of one float4 column; LDS
// reduce across row-groups; shfl_xor(4) combines the w-pair; write.
// 1024 thr/block -> 2 blocks/CU -> 32 waves/CU during the 134 MB read.
// ---------------------------------------------------------------------------
__global__ __launch_bounds__(1024) void pool_k(const float* __restrict__ fm,
                                               float* __restrict__ pooled) {
  __shared__ float4 part[3][256];   // row-groups 1..3 deposit; rg 0 reduces
  int bid = blockIdx.x;
  int wt = bid & 7;          // w tile (64 wide)
  int n  = (bid >> 3) & 7;   // pool row
  int b  = bid >> 6;
  int t  = threadIdx.x;
  int rg = t >> 8;           // row group 0..3 (16 rows each)
  int tt = t & 255;
  int wl = tt >> 2;          // 0..63
  int cq = tt & 3;           // c quad
  int w = wt * 64 + wl;

  const float* src =
      fm + ((size_t)((b * NH + n * 64 + rg * 16) * NW + w) * NC + cq * 4);
  float4 a = make_float4(0.f, 0.f, 0.f, 0.f);
#pragma unroll
  for (int dh = 0; dh < 16; ++dh) {
    float4 v = *(const float4*)(src + (size_t)dh * (NW * NC));
    a.x += v.x; a.y += v.y; a.z += v.z; a.w += v.w;
  }
  if (rg) part[rg - 1][tt] = a;
  __syncthreads();
  if (rg == 0) {
    float4 p0 = part[0][tt], p1 = part[1][tt], p2 = part[2][tt];
    a.x += p0.x + p1.x + p2.x;
    a.y += p0.y + p1.y + p2.y;
    a.z += p0.z + p1.z + p2.z;
    a.w += p0.w + p1.w + p2.w;
    // combine w and w+1 (threads tt and tt^4 share cq, differ by 1 in wl)
    a.x += __shfl_xor(a.x, 4);
    a.y += __shfl_xor(a.y, 4);
    a.z += __shfl_xor(a.z, 4);
    a.w += __shfl_xor(a.w, 4);
    if ((tt & 4) == 0) {
      int w2 = wt * 32 + (tt >> 3);
      const float s = 1.f / 128.f;
      float4 r = make_float4(a.x * s, a.y * s, a.z * s, a.w * s);
      *(float4*)(pooled + ((size_t)((b * NPOOL + n) * NW2 + w2) * NC + cq * 4)) = r;
    }
  }
}

// ---------------------------------------------------------------------------
// Kernel 2: masked 3x3 conv (middle kernel row zeroed) on pooled, both in the
// original orientation (row_op) and spatial-transposed orientation (col_op).
//   row_op[n,w2,f] = sum_{kh in {0,2}, kw, c} P[n+kh-1, w2+kw-1, c] K[kh,kw,c,f]
//   col_op[n,w2,f] = sum_{kh in {0,2}, kw, c} P[n+kw-1, w2+kh-1, c] K[kh,kw,c,f]
// Neighbor taps loaded as float4 (c-vectorized); kernel reads are L1-hot.
// ---------------------------------------------------------------------------
__global__ __launch_bounds__(256) void conv_k(const float* __restrict__ pooled,
                                              const float* __restrict__ kern,
                                              const float* __restrict__ bias,
                                              float* __restrict__ row_op,
                                              float* __restrict__ col_op) {
  int idx = blockIdx.x * 256 + threadIdx.x;
  int f  = idx & 15;
  int w2 = (idx >> 4) & 255;
  int n  = (idx >> 12) & 7;
  int b  = idx >> 15;

  bool nm = n > 0, np = n < 7, wm = w2 > 0, wp = w2 < 255;
  const float* P = pooled + (size_t)((b * NPOOL + n) * NW2 + w2) * NC;
  const int UP = -NW2 * NC, DN = NW2 * NC, LT = -NC, RT = NC;
  const float4 z = make_float4(0.f, 0.f, 0.f, 0.f);

  float accR = bias[f];
  float accC = accR;
#pragma unroll
  for (int q = 0; q < 4; ++q) {
    float4 tl = (nm && wm) ? *(const float4*)(P + UP + LT + q * 4) : z;
    float4 tc = nm         ? *(const float4*)(P + UP + q * 4)      : z;
    float4 tr = (nm && wp) ? *(const float4*)(P + UP + RT + q * 4) : z;
    float4 ml = wm         ? *(const float4*)(P + LT + q * 4)      : z;
    float4 mr = wp         ? *(const float4*)(P + RT + q * 4)      : z;
    float4 bl = (np && wm) ? *(const float4*)(P + DN + LT + q * 4) : z;
    float4 bc = np         ? *(const float4*)(P + DN + q * 4)      : z;
    float4 br = (np && wp) ? *(const float4*)(P + DN + RT + q * 4) : z;
#pragma unroll
    for (int j = 0; j < 4; ++j) {
      int c = q * 4 + j;
      float k00 = kern[((0 * 3 + 0) * 16 + c) * 16 + f];
      float k01 = kern[((0 * 3 + 1) * 16 + c) * 16 + f];
      float k02 = kern[((0 * 3 + 2) * 16 + c) * 16 + f];
      float k20 = kern[((2 * 3 + 0) * 16 + c) * 16 + f];
      float k21 = kern[((2 * 3 + 1) * 16 + c) * 16 + f];
      float k22 = kern[((2 * 3 + 2) * 16 + c) * 16 + f];
      float tlj = ((const float*)&tl)[j], tcj = ((const float*)&tc)[j];
      float trj = ((const float*)&tr)[j], mlj = ((const float*)&ml)[j];
      float mrj = ((const float*)&mr)[j], blj = ((const float*)&bl)[j];
      float bcj = ((const float*)&bc)[j], brj = ((const float*)&br)[j];
      accR += tlj * k00 + tcj * k01 + trj * k02 + blj * k20 + bcj * k21 + brj * k22;
      accC += tlj * k00 + mlj * k01 + blj * k02 + trj * k20 + mrj * k21 + brj * k22;
    }
  }
  row_op[idx] = fmaxf(accR, 0.f);
  col_op[idx] = fmaxf(accC, 0.f);
}

// ---------------------------------------------------------------------------
// Kernel 3: bilinear upsample row_op/col_op to [512,512], diff vs fm, write
// out[b,h,w, 0:16]=fm, [16:32]=fm-row_up, [32:48]=fm-col_up.
// Block = 64 consecutive pixels of one image row; 4 threads per pixel (one
// c-quad each). Results staged in LDS [64][48] so global writes are 3 fully
// contiguous float4 stores per thread; nontemporal so the 403 MB stream does
// not evict fm / row_op / col_op from L2/L3.
// ---------------------------------------------------------------------------
__global__ __launch_bounds__(256) void out_k(const float* __restrict__ fm,
                                             const float* __restrict__ row_op,
                                             const float* __restrict__ col_op,
                                             float* __restrict__ out) {
  __shared__ float lds[64 * 48];
  int bid = blockIdx.x;
  int wt = bid & 7;
  int h  = (bid >> 3) & 511;
  int b  = bid >> 12;
  int t = threadIdx.x;
  int pl = t >> 2;   // local pixel 0..63
  int cq = t & 3;    // c quad
  int w = wt * 64 + pl;

  // interpolation coords (identical for row_up and col_up):
  // n-axis: 8 -> 512, w2-axis: 256 -> 512, half-pixel, edge-clamped.
  float x  = (h + 0.5f) * (1.f / 64.f) - 0.5f;   // uniform per block
  float xf = floorf(x);
  float wx = x - xf;
  int n0  = (int)xf;
  int n0c = n0 < 0 ? 0 : n0;
  int n1c = (n0 + 1 > 7) ? 7 : n0 + 1;

  float y  = (w + 0.5f) * 0.5f - 0.5f;
  float yf = floorf(y);
  float wy = y - yf;
  int y0  = (int)yf;
  int y0c = y0 < 0 ? 0 : y0;
  int y1c = (y0 + 1 > 255) ? 255 : y0 + 1;

  float w00 = (1.f - wx) * (1.f - wy);
  float w01 = (1.f - wx) * wy;
  float w10 = wx * (1.f - wy);
  float w11 = wx * wy;

  size_t rowbase = (size_t)(b * NH + h) * NW;
  float4 fv = *(const float4*)(fm + (rowbase + w) * NC + cq * 4);

  const float* R  = row_op + (size_t)b * (NPOOL * NW2 * NC);
  const float* Cl = col_op + (size_t)b * (NPOOL * NW2 * NC);
#define TAP(A, nn, yy) (*(const float4*)((A) + ((size_t)(nn) * NW2 + (yy)) * NC + cq * 4))
  float4 r00 = TAP(R, n0c, y0c), r01 = TAP(R, n0c, y1c);
  float4 r10 = TAP(R, n1c, y0c), r11 = TAP(R, n1c, y1c);
  float4 c00 = TAP(Cl, n0c, y0c), c01 = TAP(Cl, n0c, y1c);
  float4 c10 = TAP(Cl, n1c, y0c), c11 = TAP(Cl, n1c, y1c);
#undef TAP

  float4 rup, cup;
  rup.x = w00 * r00.x + w01 * r01.x + w10 * r10.x + w11 * r11.x;
  rup.y = w00 * r00.y + w01 * r01.y + w10 * r10.y + w11 * r11.y;
  rup.z = w00 * r00.z + w01 * r01.z + w10 * r10.z + w11 * r11.z;
  rup.w = w00 * r00.w + w01 * r01.w + w10 * r10.w + w11 * r11.w;
  cup.x = w00 * c00.x + w01 * c01.x + w10 * c10.x + w11 * c11.x;
  cup.y = w00 * c00.y + w01 * c01.y + w10 * c10.y + w11 * c11.y;
  cup.z = w00 * c00.z + w01 * c01.z + w10 * c10.z + w11 * c11.z;
  cup.w = w00 * c00.w + w01 * c01.w + w10 * c10.w + w11 * c11.w;

  float* L = lds + pl * 48 + cq * 4;
  L[0]  = fv.x;          L[1]  = fv.y;          L[2]  = fv.z;          L[3]  = fv.w;
  L[16] = fv.x - rup.x;  L[17] = fv.y - rup.y;  L[18] = fv.z - rup.z;  L[19] = fv.w - rup.w;
  L[32] = fv.x - cup.x;  L[33] = fv.y - cup.y;  L[34] = fv.z - cup.z;  L[35] = fv.w - cup.w;
  __syncthreads();

  float* obase = out + ((size_t)(b * NH + h) * NW + wt * 64) * 48;
#pragma unroll
  for (int k = 0; k < 3; ++k) {
    int i = t + k * 256;
    vf4 v = *(const vf4*)(lds + i * 4);
    __builtin_nontemporal_store(v, (vf4*)(obase + (size_t)i * 4));
  }
}

extern "C" void kernel_launch(void* const* d_in, const int* in_sizes, int n_in,
                              void* d_out, int out_size, void* d_ws, size_t ws_size,
                              hipStream_t stream) {
  const float* fm   = (const float*)d_in[0];
  const float* kern = (const float*)d_in[1];
  const float* bias = (const float*)d_in[2];
  float* out = (float*)d_out;

  float* pooled = (float*)d_ws;                 // 1 MB
  float* row_op = pooled + POOL_ELEMS;          // 1 MB
  float* col_op = row_op + POOL_ELEMS;          // 1 MB

  pool_k<<<NB * NPOOL * 8, 1024, 0, stream>>>(fm, pooled);
  conv_k<<<POOL_ELEMS / 256, 256, 0, stream>>>(pooled, kern, bias, row_op, col_op);
  out_k<<<NB * NH * (NW / 64), 256, 0, stream>>>(fm, row_op, col_op, out);
}